// Round 9
// baseline (1012.412 us; speedup 1.0000x reference)
//
#include <hip/hip_runtime.h>
#include <hip/hip_bf16.h>
#include <math.h>

#define HD 128           // hidden/feature dim
#define GMAX 64          // graphs
#define SCHUNK 1024      // elements per scan block

// ---------------- init: deg=1, pooled=0 ----------------
__global__ void init_kernel(int* deg, float* pooled, int N) {
    int i = blockIdx.x * blockDim.x + threadIdx.x;
    if (i < N) deg[i] = 1;                 // self-loop
    if (i < GMAX * HD) pooled[i] = 0.0f;
}

// ---------------- degree histogram over real edges ----------------
__global__ void count_kernel(const int* dst, int* deg, int E) {
    int e = blockIdx.x * blockDim.x + threadIdx.x;
    if (e < E) atomicAdd(&deg[dst[e]], 1);
}

// ---------------- 3-phase device-wide exclusive scan of (deg-1) ----------------
__global__ __launch_bounds__(256) void scanA_kernel(const int* __restrict__ deg,
                                                    int* __restrict__ part, int N) {
    __shared__ int red[256];
    int b = blockIdx.x, t = threadIdx.x;
    int base = b * SCHUNK;
    int s = 0;
#pragma unroll
    for (int j = 0; j < SCHUNK / 256; ++j) {
        int i = base + t + j * 256;
        if (i < N) s += deg[i] - 1;
    }
    red[t] = s;
    __syncthreads();
    for (int off = 128; off > 0; off >>= 1) {
        if (t < off) red[t] += red[t + off];
        __syncthreads();
    }
    if (t == 0) part[b] = red[0];
}

__global__ __launch_bounds__(1024) void scanB_kernel(int* __restrict__ part,
                                                     int* __restrict__ row_ptr,
                                                     int nb, int N) {
    __shared__ int s[1024];
    int t = threadIdx.x;
    int v = (t < nb) ? part[t] : 0;
    s[t] = v;
    __syncthreads();
    for (int off = 1; off < 1024; off <<= 1) {
        int x = s[t];
        int u = (t >= off) ? s[t - off] : 0;
        __syncthreads();
        s[t] = x + u;
        __syncthreads();
    }
    if (t < nb) part[t] = (t > 0) ? s[t - 1] : 0;   // exclusive
    if (t == 1023) row_ptr[N] = s[1023];            // grand total
}

// C: per-block local exclusive scan + base -> row_ptr, cursor; also dis = rsqrt(deg)
__global__ __launch_bounds__(256) void scanC_kernel(const int* __restrict__ deg,
                                                    const int* __restrict__ part,
                                                    int* __restrict__ row_ptr,
                                                    int* __restrict__ cursor,
                                                    float* __restrict__ dis, int N) {
    __shared__ int red[256];
    int b = blockIdx.x, t = threadIdx.x;
    int base = b * SCHUNK;
    int i0 = base + t * 4;
    int d[4];
    int s = 0;
#pragma unroll
    for (int j = 0; j < 4; ++j) {
        int i = i0 + j;
        int dg = (i < N) ? deg[i] : 1;
        if (i < N) dis[i] = 1.0f / sqrtf((float)dg);
        d[j] = (i < N) ? dg - 1 : 0;
        s += d[j];
    }
    red[t] = s;
    __syncthreads();
    for (int off = 1; off < 256; off <<= 1) {
        int x = red[t];
        int u = (t >= off) ? red[t - off] : 0;
        __syncthreads();
        red[t] = x + u;
        __syncthreads();
    }
    int run = part[b] + ((t > 0) ? red[t - 1] : 0);
#pragma unroll
    for (int j = 0; j < 4; ++j) {
        int i = i0 + j;
        if (i < N) {
            row_ptr[i] = run;
            cursor[i] = run;
            run += d[j];
        }
    }
}

// ---------------- CSR fill: bucket edges by dst ----------------
__global__ void fill_kernel(const int* src, const int* dst, const float* dis,
                            int* cursor, int* csr_src, float* csr_w, int E) {
    int e = blockIdx.x * blockDim.x + threadIdx.x;
    if (e >= E) return;
    int s = src[e], d = dst[e];
    int p = atomicAdd(&cursor[d], 1);
    csr_src[p] = s;
    csr_w[p] = dis[s] * dis[d];
}

// ---------------- SGEMM: Hout[N,128] = A[N,128] @ W[128,128] ----------------
// BM=128, BN=128, BK=32, 256 threads (16x16), 8x8 per-thread tile.
// __launch_bounds__(256,4): 4 waves/SIMD min -> VGPR alloc <=128 -> 16 waves/CU
// (round-6 regression: 136 VGPR crossed the 128 boundary -> 8 waves/CU).
// Col/row split {t*4..+3} and {64+t*4..+3}: all inner ds_read_b128 conflict-free.
#define GBM 128
#define GBK 32
__global__ __launch_bounds__(256, 4) void gemm_kernel(const float* __restrict__ A,
                                                      const float* __restrict__ W,
                                                      float* __restrict__ Hout, int N) {
    __shared__ float At[GBK * GBM];    // [k][row] transposed
    __shared__ float Ws[GBK * 128];    // [k][col]
    int tid = threadIdx.x;
    int row0 = blockIdx.x * GBM;
    int tx = tid & 15, ty = tid >> 4;
    float acc[8][8];
#pragma unroll
    for (int i = 0; i < 8; ++i)
#pragma unroll
        for (int j = 0; j < 8; ++j) acc[i][j] = 0.0f;

    for (int kc = 0; kc < 128 / GBK; ++kc) {
        __syncthreads();
        // A tile: 128 rows x 32 k, transposed into LDS (write 2 lanes/bank = free)
#pragma unroll
        for (int it = 0; it < 4; ++it) {
            int q = tid + it * 256;      // 0..1023
            int r = q & 127;             // row in tile
            int kq = q >> 7;             // float4 group in k (0..7)
            int gr = row0 + r;
            float4 v = make_float4(0.f, 0.f, 0.f, 0.f);
            if (gr < N) v = *(const float4*)&A[(size_t)gr * 128 + kc * GBK + kq * 4];
            At[(kq * 4 + 0) * GBM + r] = v.x;
            At[(kq * 4 + 1) * GBM + r] = v.y;
            At[(kq * 4 + 2) * GBM + r] = v.z;
            At[(kq * 4 + 3) * GBM + r] = v.w;
        }
        // W tile: 32 k x 128 cols
#pragma unroll
        for (int it = 0; it < 4; ++it) {
            int q = tid + it * 256;      // 0..1023
            int jq = q & 31, kk = q >> 5;
            *(float4*)&Ws[kk * 128 + jq * 4] =
                *(const float4*)&W[(kc * GBK + kk) * 128 + jq * 4];
        }
        __syncthreads();
#pragma unroll
        for (int kk = 0; kk < GBK; ++kk) {
            float4 a0 = *(float4*)&At[kk * GBM + ty * 4];
            float4 a1 = *(float4*)&At[kk * GBM + 64 + ty * 4];
            float4 w0 = *(float4*)&Ws[kk * 128 + tx * 4];
            float4 w1 = *(float4*)&Ws[kk * 128 + 64 + tx * 4];
            // FMA directly on components (no copy arrays -> lower reg pressure)
            acc[0][0] += a0.x * w0.x; acc[0][1] += a0.x * w0.y; acc[0][2] += a0.x * w0.z; acc[0][3] += a0.x * w0.w;
            acc[0][4] += a0.x * w1.x; acc[0][5] += a0.x * w1.y; acc[0][6] += a0.x * w1.z; acc[0][7] += a0.x * w1.w;
            acc[1][0] += a0.y * w0.x; acc[1][1] += a0.y * w0.y; acc[1][2] += a0.y * w0.z; acc[1][3] += a0.y * w0.w;
            acc[1][4] += a0.y * w1.x; acc[1][5] += a0.y * w1.y; acc[1][6] += a0.y * w1.z; acc[1][7] += a0.y * w1.w;
            acc[2][0] += a0.z * w0.x; acc[2][1] += a0.z * w0.y; acc[2][2] += a0.z * w0.z; acc[2][3] += a0.z * w0.w;
            acc[2][4] += a0.z * w1.x; acc[2][5] += a0.z * w1.y; acc[2][6] += a0.z * w1.z; acc[2][7] += a0.z * w1.w;
            acc[3][0] += a0.w * w0.x; acc[3][1] += a0.w * w0.y; acc[3][2] += a0.w * w0.z; acc[3][3] += a0.w * w0.w;
            acc[3][4] += a0.w * w1.x; acc[3][5] += a0.w * w1.y; acc[3][6] += a0.w * w1.z; acc[3][7] += a0.w * w1.w;
            acc[4][0] += a1.x * w0.x; acc[4][1] += a1.x * w0.y; acc[4][2] += a1.x * w0.z; acc[4][3] += a1.x * w0.w;
            acc[4][4] += a1.x * w1.x; acc[4][5] += a1.x * w1.y; acc[4][6] += a1.x * w1.z; acc[4][7] += a1.x * w1.w;
            acc[5][0] += a1.y * w0.x; acc[5][1] += a1.y * w0.y; acc[5][2] += a1.y * w0.z; acc[5][3] += a1.y * w0.w;
            acc[5][4] += a1.y * w1.x; acc[5][5] += a1.y * w1.y; acc[5][6] += a1.y * w1.z; acc[5][7] += a1.y * w1.w;
            acc[6][0] += a1.z * w0.x; acc[6][1] += a1.z * w0.y; acc[6][2] += a1.z * w0.z; acc[6][3] += a1.z * w0.w;
            acc[6][4] += a1.z * w1.x; acc[6][5] += a1.z * w1.y; acc[6][6] += a1.z * w1.z; acc[6][7] += a1.z * w1.w;
            acc[7][0] += a1.w * w0.x; acc[7][1] += a1.w * w0.y; acc[7][2] += a1.w * w0.z; acc[7][3] += a1.w * w0.w;
            acc[7][4] += a1.w * w1.x; acc[7][5] += a1.w * w1.y; acc[7][6] += a1.w * w1.z; acc[7][7] += a1.w * w1.w;
        }
    }
#pragma unroll
    for (int i = 0; i < 8; ++i) {
        int r = row0 + ((i < 4) ? (ty * 4 + i) : (64 + ty * 4 + (i - 4)));
        if (r < N) {
            *(float4*)&Hout[(size_t)r * 128 + tx * 4] =
                make_float4(acc[i][0], acc[i][1], acc[i][2], acc[i][3]);
            *(float4*)&Hout[(size_t)r * 128 + 64 + tx * 4] =
                make_float4(acc[i][4], acc[i][5], acc[i][6], acc[i][7]);
        }
    }
}

__device__ __forceinline__ float gelu_exact(float x) {
    return 0.5f * x * (1.0f + erff(x * 0.70710678118654752f));
}

// ---------------- aggregate (CSR, node-parallel) + bias + GELU ----------------
__global__ __launch_bounds__(256) void agg_kernel(const float* __restrict__ h,
                                                  const int* __restrict__ row_ptr,
                                                  const int* __restrict__ csr_src,
                                                  const float* __restrict__ csr_w,
                                                  const float* __restrict__ dis,
                                                  const float* __restrict__ bias,
                                                  float* __restrict__ out, int N) {
    int node = blockIdx.x * 8 + (threadIdx.x >> 5);
    int lane = threadIdx.x & 31;
    if (node >= N) return;
    const float4* hv = (const float4*)h;
    float d = dis[node];
    float sw = d * d;  // self-loop norm = 1/deg
    float4 a = hv[(size_t)node * 32 + lane];
    float4 acc = make_float4(a.x * sw, a.y * sw, a.z * sw, a.w * sw);
    int p0 = row_ptr[node], p1 = row_ptr[node + 1];
    int p = p0;
    for (; p + 2 <= p1; p += 2) {
        int s0 = csr_src[p];
        int s1 = csr_src[p + 1];
        float w0 = csr_w[p];
        float w1 = csr_w[p + 1];
        float4 x0 = hv[(size_t)s0 * 32 + lane];
        float4 x1 = hv[(size_t)s1 * 32 + lane];
        acc.x += x0.x * w0; acc.y += x0.y * w0; acc.z += x0.z * w0; acc.w += x0.w * w0;
        acc.x += x1.x * w1; acc.y += x1.y * w1; acc.z += x1.z * w1; acc.w += x1.w * w1;
    }
    if (p < p1) {
        int s0 = csr_src[p];
        float w0 = csr_w[p];
        float4 x0 = hv[(size_t)s0 * 32 + lane];
        acc.x += x0.x * w0; acc.y += x0.y * w0; acc.z += x0.z * w0; acc.w += x0.w * w0;
    }
    float4 b = ((const float4*)bias)[lane];
    float4 o;
    o.x = gelu_exact(acc.x + b.x);
    o.y = gelu_exact(acc.y + b.y);
    o.z = gelu_exact(acc.z + b.z);
    o.w = gelu_exact(acc.w + b.w);
    ((float4*)out)[(size_t)node * 32 + lane] = o;
}

// ---------------- per-graph counts via binary search (batch is sorted) ----------------
__global__ void cnt_bs_kernel(const int* __restrict__ batch, int* __restrict__ cnt, int N) {
    __shared__ int lb[GMAX + 1];
    int g = threadIdx.x;   // 0..127, use 0..64
    if (g <= GMAX) {
        int lo = 0, hi = N;
        while (lo < hi) {
            int mid = (lo + hi) >> 1;
            if (batch[mid] < g) lo = mid + 1; else hi = mid;
        }
        lb[g] = lo;
    }
    __syncthreads();
    if (g < GMAX) cnt[g] = lb[g + 1] - lb[g];
}

// ---------------- pooled sums ----------------
#define PB_NODES 32
__global__ __launch_bounds__(128) void pool_kernel(const float* __restrict__ act,
                                                   const int* __restrict__ batch,
                                                   float* __restrict__ pooled, int N) {
    int f = threadIdx.x;  // 0..127
    int n0 = blockIdx.x * PB_NODES;
    int n1 = n0 + PB_NODES; if (n1 > N) n1 = N;
    int cur = -1; float sum = 0.0f;
    for (int n = n0; n < n1; ++n) {
        int g = batch[n];
        if (g != cur) {
            if (cur >= 0) atomicAdd(&pooled[cur * HD + f], sum);
            cur = g; sum = 0.0f;
        }
        sum += act[n * HD + f];
    }
    if (cur >= 0) atomicAdd(&pooled[cur * HD + f], sum);
}

// ---------------- MLP layer 1: elu(mean @ lw1 + lb1) ----------------
__global__ void mlp1_kernel(const float* __restrict__ pooled, const int* __restrict__ cnt,
                            const float* __restrict__ lw1, const float* __restrict__ lb1,
                            float* __restrict__ t1) {
    int g = blockIdx.x;      // 0..63
    int j = threadIdx.x;     // 0..63
    float invc = 1.0f / fmaxf((float)cnt[g], 1.0f);
    float s = lb1[j];
    for (int k = 0; k < HD; ++k) s += pooled[g * HD + k] * invc * lw1[k * 64 + j];
    t1[g * 64 + j] = (s > 0.0f) ? s : expm1f(s);
}

// ---------------- MLP layer 2 ----------------
__global__ void mlp2_kernel(const float* __restrict__ t1, const float* __restrict__ lw2,
                            const float* __restrict__ lb2, float* __restrict__ out) {
    int g = threadIdx.x;     // 0..63
    float s = lb2[0];
    for (int k = 0; k < 64; ++k) s += t1[g * 64 + k] * lw2[k];
    out[g] = s;
}

static inline size_t align16(size_t x) { return (x + 15) & ~(size_t)15; }

extern "C" void kernel_launch(void* const* d_in, const int* in_sizes, int n_in,
                              void* d_out, int out_size, void* d_ws, size_t ws_size,
                              hipStream_t stream) {
    const float* x   = (const float*)d_in[0];
    const float* W1  = (const float*)d_in[1];
    const float* b1  = (const float*)d_in[2];
    const float* W2  = (const float*)d_in[3];
    const float* b2  = (const float*)d_in[4];
    const float* W3  = (const float*)d_in[5];
    const float* b3  = (const float*)d_in[6];
    const float* lw1 = (const float*)d_in[7];
    const float* lb1 = (const float*)d_in[8];
    const float* lw2 = (const float*)d_in[9];
    const float* lb2 = (const float*)d_in[10];
    const int* eidx  = (const int*)d_in[11];
    const int* batch = (const int*)d_in[12];

    const int N = in_sizes[0] / HD;
    const int E = in_sizes[11] / 2;
    const int* src = eidx;
    const int* dst = eidx + E;

    float* out = (float*)d_out;

    // workspace layout
    char* ws = (char*)d_ws;
    size_t off = 0;
    float* act = (float*)(ws + off); off += align16((size_t)N * HD * 4);
    float* h   = (float*)(ws + off); off += align16((size_t)N * HD * 4);
    int* deg   = (int*)(ws + off);   off += align16((size_t)N * 4);
    float* dis = (float*)(ws + off); off += align16((size_t)N * 4);
    int* row_ptr = (int*)(ws + off); off += align16((size_t)(N + 1) * 4);
    int* cursor  = (int*)(ws + off); off += align16((size_t)N * 4);
    int* csr_src = (int*)(ws + off); off += align16((size_t)E * 4);
    float* csr_w = (float*)(ws + off); off += align16((size_t)E * 4);
    float* pooled = (float*)(ws + off); off += align16((size_t)GMAX * HD * 4);
    int* cnt = (int*)(ws + off); off += align16((size_t)GMAX * 4);
    float* t1 = (float*)(ws + off); off += align16((size_t)GMAX * 64 * 4);
    int* part = (int*)(ws + off); off += align16((size_t)1024 * 4);
    (void)ws_size; (void)n_in; (void)out_size;

    int nb_n = (N + 255) / 256;
    int nb_e = (E + 255) / 256;
    int nb_s = (N + SCHUNK - 1) / SCHUNK;

    // graph structure
    hipLaunchKernelGGL(init_kernel, dim3(nb_n), dim3(256), 0, stream, deg, pooled, N);
    hipLaunchKernelGGL(count_kernel, dim3(nb_e), dim3(256), 0, stream, dst, deg, E);
    hipLaunchKernelGGL(scanA_kernel, dim3(nb_s), dim3(256), 0, stream, deg, part, N);
    hipLaunchKernelGGL(scanB_kernel, dim3(1), dim3(1024), 0, stream, part, row_ptr, nb_s, N);
    hipLaunchKernelGGL(scanC_kernel, dim3(nb_s), dim3(256), 0, stream, deg, part, row_ptr, cursor, dis, N);
    hipLaunchKernelGGL(fill_kernel, dim3(nb_e), dim3(256), 0, stream, src, dst, dis, cursor, csr_src, csr_w, E);

    int nb_g = (N + GBM - 1) / GBM; // gemm blocks (782)
    int nb_a = (N + 7) / 8;         // agg blocks

    // layer 1
    hipLaunchKernelGGL(gemm_kernel, dim3(nb_g), dim3(256), 0, stream, x, W1, h, N);
    hipLaunchKernelGGL(agg_kernel, dim3(nb_a), dim3(256), 0, stream, h, row_ptr, csr_src, csr_w, dis, b1, act, N);
    // layer 2
    hipLaunchKernelGGL(gemm_kernel, dim3(nb_g), dim3(256), 0, stream, act, W2, h, N);
    hipLaunchKernelGGL(agg_kernel, dim3(nb_a), dim3(256), 0, stream, h, row_ptr, csr_src, csr_w, dis, b2, act, N);
    // layer 3
    hipLaunchKernelGGL(gemm_kernel, dim3(nb_g), dim3(256), 0, stream, act, W3, h, N);
    hipLaunchKernelGGL(agg_kernel, dim3(nb_a), dim3(256), 0, stream, h, row_ptr, csr_src, csr_w, dis, b3, act, N);

    // pooling + MLP head
    hipLaunchKernelGGL(cnt_bs_kernel, dim3(1), dim3(128), 0, stream, batch, cnt, N);
    int nb_p = (N + PB_NODES - 1) / PB_NODES;
    hipLaunchKernelGGL(pool_kernel, dim3(nb_p), dim3(128), 0, stream, act, batch, pooled, N);
    hipLaunchKernelGGL(mlp1_kernel, dim3(GMAX), dim3(64), 0, stream, pooled, cnt, lw1, lb1, t1);
    hipLaunchKernelGGL(mlp2_kernel, dim3(1), dim3(GMAX), 0, stream, t1, lw2, lb2, out);
}

// Round 11
// 519.159 us; speedup vs baseline: 1.9501x; 1.9501x over previous
//
#include <hip/hip_runtime.h>
#include <hip/hip_bf16.h>
#include <math.h>

#define HD 128           // hidden/feature dim
#define GMAX 64          // graphs
#define SCHUNK 1024      // elements per scan block

// ---------------- init: deg=1, pooled=0 ----------------
__global__ void init_kernel(int* deg, float* pooled, int N) {
    int i = blockIdx.x * blockDim.x + threadIdx.x;
    if (i < N) deg[i] = 1;                 // self-loop
    if (i < GMAX * HD) pooled[i] = 0.0f;
}

// ---------------- degree histogram over real edges ----------------
__global__ void count_kernel(const int* dst, int* deg, int E) {
    int e = blockIdx.x * blockDim.x + threadIdx.x;
    if (e < E) atomicAdd(&deg[dst[e]], 1);
}

// ---------------- 3-phase device-wide exclusive scan of (deg-1) ----------------
__global__ __launch_bounds__(256) void scanA_kernel(const int* __restrict__ deg,
                                                    int* __restrict__ part, int N) {
    __shared__ int red[256];
    int b = blockIdx.x, t = threadIdx.x;
    int base = b * SCHUNK;
    int s = 0;
#pragma unroll
    for (int j = 0; j < SCHUNK / 256; ++j) {
        int i = base + t + j * 256;
        if (i < N) s += deg[i] - 1;
    }
    red[t] = s;
    __syncthreads();
    for (int off = 128; off > 0; off >>= 1) {
        if (t < off) red[t] += red[t + off];
        __syncthreads();
    }
    if (t == 0) part[b] = red[0];
}

__global__ __launch_bounds__(1024) void scanB_kernel(int* __restrict__ part,
                                                     int* __restrict__ row_ptr,
                                                     int nb, int N) {
    __shared__ int s[1024];
    int t = threadIdx.x;
    int v = (t < nb) ? part[t] : 0;
    s[t] = v;
    __syncthreads();
    for (int off = 1; off < 1024; off <<= 1) {
        int x = s[t];
        int u = (t >= off) ? s[t - off] : 0;
        __syncthreads();
        s[t] = x + u;
        __syncthreads();
    }
    if (t < nb) part[t] = (t > 0) ? s[t - 1] : 0;   // exclusive
    if (t == 1023) row_ptr[N] = s[1023];            // grand total
}

// C: per-block local exclusive scan + base -> row_ptr, cursor; also dis = rsqrt(deg)
__global__ __launch_bounds__(256) void scanC_kernel(const int* __restrict__ deg,
                                                    const int* __restrict__ part,
                                                    int* __restrict__ row_ptr,
                                                    int* __restrict__ cursor,
                                                    float* __restrict__ dis, int N) {
    __shared__ int red[256];
    int b = blockIdx.x, t = threadIdx.x;
    int base = b * SCHUNK;
    int i0 = base + t * 4;
    int d[4];
    int s = 0;
#pragma unroll
    for (int j = 0; j < 4; ++j) {
        int i = i0 + j;
        int dg = (i < N) ? deg[i] : 1;
        if (i < N) dis[i] = 1.0f / sqrtf((float)dg);
        d[j] = (i < N) ? dg - 1 : 0;
        s += d[j];
    }
    red[t] = s;
    __syncthreads();
    for (int off = 1; off < 256; off <<= 1) {
        int x = red[t];
        int u = (t >= off) ? red[t - off] : 0;
        __syncthreads();
        red[t] = x + u;
        __syncthreads();
    }
    int run = part[b] + ((t > 0) ? red[t - 1] : 0);
#pragma unroll
    for (int j = 0; j < 4; ++j) {
        int i = i0 + j;
        if (i < N) {
            row_ptr[i] = run;
            cursor[i] = run;
            run += d[j];
        }
    }
}

// ---------------- CSR fill: bucket edges by dst ----------------
__global__ void fill_kernel(const int* src, const int* dst, const float* dis,
                            int* cursor, int* csr_src, float* csr_w, int E) {
    int e = blockIdx.x * blockDim.x + threadIdx.x;
    if (e >= E) return;
    int s = src[e], d = dst[e];
    int p = atomicAdd(&cursor[d], 1);
    csr_src[p] = s;
    csr_w[p] = dis[s] * dis[d];
}

// ---------------- SGEMM: Hout[N,128] = A[N,128] @ W[128,128] ----------------
// Round-5 proven structure (BM=64, BN=128, BK=32, 256 thr, 4x8 tile, ~60 VGPR)
// + round-6's proven conflict-free column split: cols {tx*4..+3, 64+tx*4..+3}.
// All three inner ds_read_b128 now hit <=2 addrs/bank (free per m136);
// the old tx*8 layout was a 4-way conflict (6.4M cycles measured).
// NO __launch_bounds__ min-waves (round-9 lesson: forcing it spills acc to scratch).
__global__ __launch_bounds__(256) void gemm_kernel(const float* __restrict__ A,
                                                   const float* __restrict__ W,
                                                   float* __restrict__ Hout, int N) {
    __shared__ float At[32 * 64];    // [k][row] transposed
    __shared__ float Ws[32 * 128];   // [k][col]
    int tid = threadIdx.x;
    int row0 = blockIdx.x * 64;
    int tx = tid & 15, ty = tid >> 4;
    float acc[4][8];
#pragma unroll
    for (int i = 0; i < 4; ++i)
#pragma unroll
        for (int j = 0; j < 8; ++j) acc[i][j] = 0.0f;

    for (int kc = 0; kc < 4; ++kc) {
        __syncthreads();
        // A tile: 64 rows x 32 k, transposed into LDS
#pragma unroll
        for (int it = 0; it < 2; ++it) {
            int q = tid + it * 256;      // 0..511
            int r = q & 63, kq = q >> 6; // kq 0..7
            int grow = row0 + r;
            float4 v = make_float4(0.f, 0.f, 0.f, 0.f);
            if (grow < N) v = *(const float4*)&A[(size_t)grow * 128 + kc * 32 + kq * 4];
            At[(kq * 4 + 0) * 64 + r] = v.x;
            At[(kq * 4 + 1) * 64 + r] = v.y;
            At[(kq * 4 + 2) * 64 + r] = v.z;
            At[(kq * 4 + 3) * 64 + r] = v.w;
        }
        // W tile: 32 k x 128 cols
#pragma unroll
        for (int it = 0; it < 4; ++it) {
            int q = tid + it * 256;      // 0..1023
            int jq = q & 31, kk = q >> 5;
            *(float4*)&Ws[kk * 128 + jq * 4] =
                *(const float4*)&W[(kc * 32 + kk) * 128 + jq * 4];
        }
        __syncthreads();
#pragma unroll
        for (int kk = 0; kk < 32; ++kk) {
            float4 a  = *(float4*)&At[kk * 64 + ty * 4];
            float4 w0 = *(float4*)&Ws[kk * 128 + tx * 4];
            float4 w1 = *(float4*)&Ws[kk * 128 + 64 + tx * 4];
            acc[0][0] += a.x * w0.x; acc[0][1] += a.x * w0.y; acc[0][2] += a.x * w0.z; acc[0][3] += a.x * w0.w;
            acc[0][4] += a.x * w1.x; acc[0][5] += a.x * w1.y; acc[0][6] += a.x * w1.z; acc[0][7] += a.x * w1.w;
            acc[1][0] += a.y * w0.x; acc[1][1] += a.y * w0.y; acc[1][2] += a.y * w0.z; acc[1][3] += a.y * w0.w;
            acc[1][4] += a.y * w1.x; acc[1][5] += a.y * w1.y; acc[1][6] += a.y * w1.z; acc[1][7] += a.y * w1.w;
            acc[2][0] += a.z * w0.x; acc[2][1] += a.z * w0.y; acc[2][2] += a.z * w0.z; acc[2][3] += a.z * w0.w;
            acc[2][4] += a.z * w1.x; acc[2][5] += a.z * w1.y; acc[2][6] += a.z * w1.z; acc[2][7] += a.z * w1.w;
            acc[3][0] += a.w * w0.x; acc[3][1] += a.w * w0.y; acc[3][2] += a.w * w0.z; acc[3][3] += a.w * w0.w;
            acc[3][4] += a.w * w1.x; acc[3][5] += a.w * w1.y; acc[3][6] += a.w * w1.z; acc[3][7] += a.w * w1.w;
        }
    }
#pragma unroll
    for (int i = 0; i < 4; ++i) {
        int r = row0 + ty * 4 + i;
        if (r < N) {
            *(float4*)&Hout[(size_t)r * 128 + tx * 4] =
                make_float4(acc[i][0], acc[i][1], acc[i][2], acc[i][3]);
            *(float4*)&Hout[(size_t)r * 128 + 64 + tx * 4] =
                make_float4(acc[i][4], acc[i][5], acc[i][6], acc[i][7]);
        }
    }
}

__device__ __forceinline__ float gelu_exact(float x) {
    return 0.5f * x * (1.0f + erff(x * 0.70710678118654752f));
}

// ---------------- aggregate (CSR, node-parallel) + bias + GELU ----------------
__global__ __launch_bounds__(256) void agg_kernel(const float* __restrict__ h,
                                                  const int* __restrict__ row_ptr,
                                                  const int* __restrict__ csr_src,
                                                  const float* __restrict__ csr_w,
                                                  const float* __restrict__ dis,
                                                  const float* __restrict__ bias,
                                                  float* __restrict__ out, int N) {
    int node = blockIdx.x * 8 + (threadIdx.x >> 5);
    int lane = threadIdx.x & 31;
    if (node >= N) return;
    const float4* hv = (const float4*)h;
    float d = dis[node];
    float sw = d * d;  // self-loop norm = 1/deg
    float4 a = hv[(size_t)node * 32 + lane];
    float4 acc = make_float4(a.x * sw, a.y * sw, a.z * sw, a.w * sw);
    int p0 = row_ptr[node], p1 = row_ptr[node + 1];
    int p = p0;
    for (; p + 2 <= p1; p += 2) {
        int s0 = csr_src[p];
        int s1 = csr_src[p + 1];
        float w0 = csr_w[p];
        float w1 = csr_w[p + 1];
        float4 x0 = hv[(size_t)s0 * 32 + lane];
        float4 x1 = hv[(size_t)s1 * 32 + lane];
        acc.x += x0.x * w0; acc.y += x0.y * w0; acc.z += x0.z * w0; acc.w += x0.w * w0;
        acc.x += x1.x * w1; acc.y += x1.y * w1; acc.z += x1.z * w1; acc.w += x1.w * w1;
    }
    if (p < p1) {
        int s0 = csr_src[p];
        float w0 = csr_w[p];
        float4 x0 = hv[(size_t)s0 * 32 + lane];
        acc.x += x0.x * w0; acc.y += x0.y * w0; acc.z += x0.z * w0; acc.w += x0.w * w0;
    }
    float4 b = ((const float4*)bias)[lane];
    float4 o;
    o.x = gelu_exact(acc.x + b.x);
    o.y = gelu_exact(acc.y + b.y);
    o.z = gelu_exact(acc.z + b.z);
    o.w = gelu_exact(acc.w + b.w);
    ((float4*)out)[(size_t)node * 32 + lane] = o;
}

// ---------------- per-graph counts via binary search (batch is sorted) ----------------
__global__ void cnt_bs_kernel(const int* __restrict__ batch, int* __restrict__ cnt, int N) {
    __shared__ int lb[GMAX + 1];
    int g = threadIdx.x;   // 0..127, use 0..64
    if (g <= GMAX) {
        int lo = 0, hi = N;
        while (lo < hi) {
            int mid = (lo + hi) >> 1;
            if (batch[mid] < g) lo = mid + 1; else hi = mid;
        }
        lb[g] = lo;
    }
    __syncthreads();
    if (g < GMAX) cnt[g] = lb[g + 1] - lb[g];
}

// ---------------- pooled sums ----------------
#define PB_NODES 32
__global__ __launch_bounds__(128) void pool_kernel(const float* __restrict__ act,
                                                   const int* __restrict__ batch,
                                                   float* __restrict__ pooled, int N) {
    int f = threadIdx.x;  // 0..127
    int n0 = blockIdx.x * PB_NODES;
    int n1 = n0 + PB_NODES; if (n1 > N) n1 = N;
    int cur = -1; float sum = 0.0f;
    for (int n = n0; n < n1; ++n) {
        int g = batch[n];
        if (g != cur) {
            if (cur >= 0) atomicAdd(&pooled[cur * HD + f], sum);
            cur = g; sum = 0.0f;
        }
        sum += act[n * HD + f];
    }
    if (cur >= 0) atomicAdd(&pooled[cur * HD + f], sum);
}

// ---------------- MLP layer 1: elu(mean @ lw1 + lb1) ----------------
__global__ void mlp1_kernel(const float* __restrict__ pooled, const int* __restrict__ cnt,
                            const float* __restrict__ lw1, const float* __restrict__ lb1,
                            float* __restrict__ t1) {
    int g = blockIdx.x;      // 0..63
    int j = threadIdx.x;     // 0..63
    float invc = 1.0f / fmaxf((float)cnt[g], 1.0f);
    float s = lb1[j];
    for (int k = 0; k < HD; ++k) s += pooled[g * HD + k] * invc * lw1[k * 64 + j];
    t1[g * 64 + j] = (s > 0.0f) ? s : expm1f(s);
}

// ---------------- MLP layer 2 ----------------
__global__ void mlp2_kernel(const float* __restrict__ t1, const float* __restrict__ lw2,
                            const float* __restrict__ lb2, float* __restrict__ out) {
    int g = threadIdx.x;     // 0..63
    float s = lb2[0];
    for (int k = 0; k < 64; ++k) s += t1[g * 64 + k] * lw2[k];
    out[g] = s;
}

static inline size_t align16(size_t x) { return (x + 15) & ~(size_t)15; }

extern "C" void kernel_launch(void* const* d_in, const int* in_sizes, int n_in,
                              void* d_out, int out_size, void* d_ws, size_t ws_size,
                              hipStream_t stream) {
    const float* x   = (const float*)d_in[0];
    const float* W1  = (const float*)d_in[1];
    const float* b1  = (const float*)d_in[2];
    const float* W2  = (const float*)d_in[3];
    const float* b2  = (const float*)d_in[4];
    const float* W3  = (const float*)d_in[5];
    const float* b3  = (const float*)d_in[6];
    const float* lw1 = (const float*)d_in[7];
    const float* lb1 = (const float*)d_in[8];
    const float* lw2 = (const float*)d_in[9];
    const float* lb2 = (const float*)d_in[10];
    const int* eidx  = (const int*)d_in[11];
    const int* batch = (const int*)d_in[12];

    const int N = in_sizes[0] / HD;
    const int E = in_sizes[11] / 2;
    const int* src = eidx;
    const int* dst = eidx + E;

    float* out = (float*)d_out;

    // workspace layout
    char* ws = (char*)d_ws;
    size_t off = 0;
    float* act = (float*)(ws + off); off += align16((size_t)N * HD * 4);
    float* h   = (float*)(ws + off); off += align16((size_t)N * HD * 4);
    int* deg   = (int*)(ws + off);   off += align16((size_t)N * 4);
    float* dis = (float*)(ws + off); off += align16((size_t)N * 4);
    int* row_ptr = (int*)(ws + off); off += align16((size_t)(N + 1) * 4);
    int* cursor  = (int*)(ws + off); off += align16((size_t)N * 4);
    int* csr_src = (int*)(ws + off); off += align16((size_t)E * 4);
    float* csr_w = (float*)(ws + off); off += align16((size_t)E * 4);
    float* pooled = (float*)(ws + off); off += align16((size_t)GMAX * HD * 4);
    int* cnt = (int*)(ws + off); off += align16((size_t)GMAX * 4);
    float* t1 = (float*)(ws + off); off += align16((size_t)GMAX * 64 * 4);
    int* part = (int*)(ws + off); off += align16((size_t)1024 * 4);
    (void)ws_size; (void)n_in; (void)out_size;

    int nb_n = (N + 255) / 256;
    int nb_e = (E + 255) / 256;
    int nb_s = (N + SCHUNK - 1) / SCHUNK;

    // graph structure
    hipLaunchKernelGGL(init_kernel, dim3(nb_n), dim3(256), 0, stream, deg, pooled, N);
    hipLaunchKernelGGL(count_kernel, dim3(nb_e), dim3(256), 0, stream, dst, deg, E);
    hipLaunchKernelGGL(scanA_kernel, dim3(nb_s), dim3(256), 0, stream, deg, part, N);
    hipLaunchKernelGGL(scanB_kernel, dim3(1), dim3(1024), 0, stream, part, row_ptr, nb_s, N);
    hipLaunchKernelGGL(scanC_kernel, dim3(nb_s), dim3(256), 0, stream, deg, part, row_ptr, cursor, dis, N);
    hipLaunchKernelGGL(fill_kernel, dim3(nb_e), dim3(256), 0, stream, src, dst, dis, cursor, csr_src, csr_w, E);

    int nb_g = (N + 63) / 64;       // gemm blocks (1563)
    int nb_a = (N + 7) / 8;         // agg blocks

    // layer 1
    hipLaunchKernelGGL(gemm_kernel, dim3(nb_g), dim3(256), 0, stream, x, W1, h, N);
    hipLaunchKernelGGL(agg_kernel, dim3(nb_a), dim3(256), 0, stream, h, row_ptr, csr_src, csr_w, dis, b1, act, N);
    // layer 2
    hipLaunchKernelGGL(gemm_kernel, dim3(nb_g), dim3(256), 0, stream, act, W2, h, N);
    hipLaunchKernelGGL(agg_kernel, dim3(nb_a), dim3(256), 0, stream, h, row_ptr, csr_src, csr_w, dis, b2, act, N);
    // layer 3
    hipLaunchKernelGGL(gemm_kernel, dim3(nb_g), dim3(256), 0, stream, act, W3, h, N);
    hipLaunchKernelGGL(agg_kernel, dim3(nb_a), dim3(256), 0, stream, h, row_ptr, csr_src, csr_w, dis, b3, act, N);

    // pooling + MLP head
    hipLaunchKernelGGL(cnt_bs_kernel, dim3(1), dim3(128), 0, stream, batch, cnt, N);
    int nb_p = (N + PB_NODES - 1) / PB_NODES;
    hipLaunchKernelGGL(pool_kernel, dim3(nb_p), dim3(128), 0, stream, act, batch, pooled, N);
    hipLaunchKernelGGL(mlp1_kernel, dim3(GMAX), dim3(64), 0, stream, pooled, cnt, lw1, lb1, t1);
    hipLaunchKernelGGL(mlp2_kernel, dim3(1), dim3(GMAX), 0, stream, t1, lw2, lb2, out);
}